// Round 7
// baseline (96.681 us; speedup 1.0000x reference)
//
#include <hip/hip_runtime.h>
#include <math.h>

#define NB 8
#define PP 4096
#define MM 2048
#define DIRS 2
#define QSLICES 16
#define QS (PP / QSLICES)       // 256 q's staged per block
#define NPTS 8                  // points per thread
#define PCHUNK (256 * NPTS)     // 2048 p's per block
#define NPBLK (PP / PCHUNK)     // 2
#define NMIN (DIRS * NB * PP)   // 65536 slots
#define NLIK (NB * MM)          // 16384
#define REP 4                   // DIAGNOSTIC: repeat inner scan (idempotent)

typedef float v2f __attribute__((ext_vector_type(2)));

// ---------------- chamfer partial mins (round-4 kernel + REP) ----------------
__global__ __launch_bounds__(256, 2) void chamfer_kernel(const float* __restrict__ x,
                                                         const float* __restrict__ y,
                                                         float* __restrict__ wspart) {
    int bx = blockIdx.x;
    int qs  = bx & (QSLICES - 1); bx >>= 4;
    int pc  = bx & (NPBLK - 1);   bx >>= 1;
    int n   = bx & (NB - 1);      bx >>= 3;
    int dir = bx;
    const float* a = dir ? y : x;
    const float* b = dir ? x : y;
    const float* an = a + (size_t)n * PP * 3;
    const float* bn = b + (size_t)n * PP * 3;

    // pk-pair layout: lds[2j]   = {-2y0[2j], -2y0[2j+1], -2y1[2j], -2y1[2j+1]}
    //                 lds[2j+1] = {-2y2[2j], -2y2[2j+1],  ys[2j],   ys[2j+1]}
    __shared__ float4 lds[QS];   // 256 float4 = 4 KiB
    int t = threadIdx.x;

    float X0[NPTS], X1[NPTS], X2[NPTS], XS[NPTS], M[NPTS];
    #pragma unroll
    for (int i = 0; i < NPTS; ++i) {
        int p = pc * PCHUNK + i * 256 + t;
        const float* ap = an + (size_t)p * 3;
        X0[i] = ap[0]; X1[i] = ap[1]; X2[i] = ap[2];
        XS[i] = X0[i] * X0[i] + X1[i] * X1[i] + X2[i] * X2[i];
        M[i] = INFINITY;
    }

    {   // stage q-slice
        int q = qs * QS + t;
        const float* bp = bn + (size_t)q * 3;
        float y0 = bp[0], y1 = bp[1], y2 = bp[2];
        int j = t >> 1, par = t & 1;
        float* base = (float*)&lds[2 * j];
        base[0 + par] = -2.f * y0;
        base[2 + par] = -2.f * y1;
        base[4 + par] = -2.f * y2;
        base[6 + par] = y0 * y0 + y1 * y1 + y2 * y2;
    }
    __syncthreads();

    for (int r = 0; r < REP; ++r) {
        #pragma unroll 2
        for (int j = 0; j < QS / 2; ++j) {
            float4 A = lds[2 * j];
            float4 B = lds[2 * j + 1];
            v2f Y0 = {A.x, A.y}, Y1 = {A.z, A.w}, Y2 = {B.x, B.y}, YS = {B.z, B.w};
            #pragma unroll
            for (int i = 0; i < NPTS; ++i) {
                v2f x0 = {X0[i], X0[i]}, x1 = {X1[i], X1[i]}, x2 = {X2[i], X2[i]};
                v2f d = __builtin_elementwise_fma(x0, Y0,
                        __builtin_elementwise_fma(x1, Y1,
                        __builtin_elementwise_fma(x2, Y2, YS)));
                M[i] = fminf(fminf(M[i], d.x), d.y);
            }
        }
        // keep reps from being CSE'd away; min over identical values is idempotent
        #pragma unroll
        for (int i = 0; i < NPTS; ++i) asm volatile("" : "+v"(M[i]));
    }

    float* plane = wspart + (size_t)qs * NMIN;
    int slot = (dir * NB + n) * PP + pc * PCHUNK + t;
    #pragma unroll
    for (int i = 0; i < NPTS; ++i)
        plane[slot + i * 256] = M[i] + XS[i];
}

// ---------------- reduce planes + log2sum + finalize (fused) ----------------
__global__ __launch_bounds__(256) void reduce_kernel(const float* __restrict__ wspart,
                                                     const float* __restrict__ lik,
                                                     float* __restrict__ wssum,  // [0..2]=sums, [3]=ticket
                                                     float* __restrict__ out) {
    int t = blockIdx.x * 256 + threadIdx.x;
    float m = wspart[t];
    #pragma unroll
    for (int s = 1; s < QSLICES; ++s)
        m = fminf(m, wspart[(size_t)s * NMIN + t]);

    float l = 0.f;
    if (t < NLIK) l = __log2f(lik[t]);

    #pragma unroll
    for (int off = 32; off > 0; off >>= 1) {
        m += __shfl_down(m, off, 64);
        l += __shfl_down(l, off, 64);
    }
    __shared__ float rm[4], rl[4];
    int lane = threadIdx.x & 63, wid = threadIdx.x >> 6;
    if (lane == 0) { rm[wid] = m; rl[wid] = l; }
    __syncthreads();
    if (threadIdx.x == 0) {
        int dir = blockIdx.x >> 7;
        atomicAdd(&wssum[dir], rm[0] + rm[1] + rm[2] + rm[3]);
        if (blockIdx.x < 64)
            atomicAdd(&wssum[2], rl[0] + rl[1] + rl[2] + rl[3]);
        __threadfence();
        unsigned done = atomicAdd((unsigned*)&wssum[3], 1u);
        if (done == 255u) {
            __threadfence();
            float s0 = __hip_atomic_load(&wssum[0], __ATOMIC_ACQUIRE, __HIP_MEMORY_SCOPE_AGENT);
            float s1 = __hip_atomic_load(&wssum[1], __ATOMIC_ACQUIRE, __HIP_MEMORY_SCOPE_AGENT);
            float s2 = __hip_atomic_load(&wssum[2], __ATOMIC_ACQUIRE, __HIP_MEMORY_SCOPE_AGENT);
            float rec = s0 / (float)(NB * PP) + s1 / (float)(NB * PP);
            float bit_y = s2 / (-(float)NB);
            float bpp = bit_y / (float)PP;
            out[0] = bpp + 1.0f * rec;  // loss (LMBDA = 1)
            out[1] = bpp;               // bpp_loss
            out[2] = rec;               // rec_loss
            out[3] = bit_y;             // bit_loss
            out[4] = bpp;               // bpp_y
        }
    }
}

extern "C" void kernel_launch(void* const* d_in, const int* in_sizes, int n_in,
                              void* d_out, int out_size, void* d_ws, size_t ws_size,
                              hipStream_t stream) {
    const float* x_hat  = (const float*)d_in[0];
    const float* points = (const float*)d_in[1];
    const float* lik    = (const float*)d_in[2];
    float* out = (float*)d_out;
    float* wssum  = (float*)d_ws;          // 4 floats: sums + ticket
    float* wspart = (float*)d_ws + 16;     // 16 planes x 65536 floats = 4 MB

    hipMemsetAsync(wssum, 0, 16, stream);
    chamfer_kernel<<<DIRS * NB * NPBLK * QSLICES, 256, 0, stream>>>(x_hat, points, wspart);
    reduce_kernel<<<256, 256, 0, stream>>>(wspart, lik, wssum, out);
}

// Round 8
// 51.569 us; speedup vs baseline: 1.8748x; 1.8748x over previous
//
#include <hip/hip_runtime.h>
#include <math.h>

#define NB 8
#define PP 4096
#define MM 2048
#define DIRS 2
#define QSLICES 16
#define QS (PP / QSLICES)       // 256 q's staged per block
#define NPTS 16                 // points per thread -> PCHUNK = 4096 = PP
#define NMIN (DIRS * NB * PP)   // 65536 slots
#define NLIK (NB * MM)          // 16384

// ---------------- chamfer partial mins: 256 blocks = 1 per CU ----------------
// grid = 2*8*16 = 256 blocks x 256 threads. Each thread owns 16 p's, scans a
// 256-q LDS slice with register prefetch; writes (min + |x|^2) to
// plane wspart[qs][slot]. Perfectly balanced: every CU does identical work.
__global__ __launch_bounds__(256, 1) void chamfer_kernel(const float* __restrict__ x,
                                                         const float* __restrict__ y,
                                                         float* __restrict__ wspart) {
    int bx = blockIdx.x;
    int qs  = bx & (QSLICES - 1); bx >>= 4;
    int n   = bx & (NB - 1);      bx >>= 3;
    int dir = bx;
    const float* a = dir ? y : x;
    const float* b = dir ? x : y;
    const float* an = a + (size_t)n * PP * 3;
    const float* bn = b + (size_t)n * PP * 3;

    __shared__ float4 lds[QS + 2];   // +2 pad: prefetch overruns harmlessly
    int t = threadIdx.x;

    float X0[NPTS], X1[NPTS], X2[NPTS], XS[NPTS], M[NPTS];
    #pragma unroll
    for (int i = 0; i < NPTS; ++i) {
        int p = i * 256 + t;
        const float* ap = an + (size_t)p * 3;
        X0[i] = ap[0]; X1[i] = ap[1]; X2[i] = ap[2];
        XS[i] = X0[i] * X0[i] + X1[i] * X1[i] + X2[i] * X2[i];
        M[i] = INFINITY;
    }

    {   // stage q-slice: lds[q] = {-2y0, -2y1, -2y2, |y|^2}
        int q = qs * QS + t;
        const float* bp = bn + (size_t)q * 3;
        float y0 = bp[0], y1 = bp[1], y2 = bp[2];
        lds[t] = make_float4(-2.f * y0, -2.f * y1, -2.f * y2,
                             y0 * y0 + y1 * y1 + y2 * y2);
        if (t < 2) lds[QS + t] = make_float4(0.f, 0.f, 0.f, 0.f);  // pad
    }
    __syncthreads();

    // register-prefetched scan: consume pair j while loading pair j+1
    float4 A = lds[0], B = lds[1];
    #pragma unroll 2
    for (int j = 0; j < QS / 2; ++j) {
        float4 A2 = lds[2 * j + 2];
        float4 B2 = lds[2 * j + 3];
        #pragma unroll
        for (int i = 0; i < NPTS; ++i) {
            float d0 = fmaf(X0[i], A.x, fmaf(X1[i], A.y, fmaf(X2[i], A.z, A.w)));
            float d1 = fmaf(X0[i], B.x, fmaf(X1[i], B.y, fmaf(X2[i], B.z, B.w)));
            M[i] = fminf(fminf(M[i], d0), d1);   // v_min3_f32
        }
        A = A2; B = B2;
    }

    float* plane = wspart + (size_t)qs * NMIN;
    int slot = (dir * NB + n) * PP + t;
    #pragma unroll
    for (int i = 0; i < NPTS; ++i)
        plane[slot + i * 256] = M[i] + XS[i];   // coalesced, no atomics, no init
}

// ---------------- reduce planes + log2sum + finalize (fused) ----------------
__global__ __launch_bounds__(256) void reduce_kernel(const float* __restrict__ wspart,
                                                     const float* __restrict__ lik,
                                                     float* __restrict__ wssum,  // [0..2]=sums, [3]=ticket
                                                     float* __restrict__ out) {
    int t = blockIdx.x * 256 + threadIdx.x;
    float m = wspart[t];
    #pragma unroll
    for (int s = 1; s < QSLICES; ++s)
        m = fminf(m, wspart[(size_t)s * NMIN + t]);

    float l = 0.f;
    if (t < NLIK) l = __log2f(lik[t]);

    #pragma unroll
    for (int off = 32; off > 0; off >>= 1) {
        m += __shfl_down(m, off, 64);
        l += __shfl_down(l, off, 64);
    }
    __shared__ float rm[4], rl[4];
    int lane = threadIdx.x & 63, wid = threadIdx.x >> 6;
    if (lane == 0) { rm[wid] = m; rl[wid] = l; }
    __syncthreads();
    if (threadIdx.x == 0) {
        int dir = blockIdx.x >> 7;
        atomicAdd(&wssum[dir], rm[0] + rm[1] + rm[2] + rm[3]);
        if (blockIdx.x < 64)
            atomicAdd(&wssum[2], rl[0] + rl[1] + rl[2] + rl[3]);
        __threadfence();
        unsigned done = atomicAdd((unsigned*)&wssum[3], 1u);
        if (done == 255u) {
            __threadfence();
            float s0 = __hip_atomic_load(&wssum[0], __ATOMIC_ACQUIRE, __HIP_MEMORY_SCOPE_AGENT);
            float s1 = __hip_atomic_load(&wssum[1], __ATOMIC_ACQUIRE, __HIP_MEMORY_SCOPE_AGENT);
            float s2 = __hip_atomic_load(&wssum[2], __ATOMIC_ACQUIRE, __HIP_MEMORY_SCOPE_AGENT);
            float rec = s0 / (float)(NB * PP) + s1 / (float)(NB * PP);
            float bit_y = s2 / (-(float)NB);
            float bpp = bit_y / (float)PP;
            out[0] = bpp + 1.0f * rec;  // loss (LMBDA = 1)
            out[1] = bpp;               // bpp_loss
            out[2] = rec;               // rec_loss
            out[3] = bit_y;             // bit_loss
            out[4] = bpp;               // bpp_y
        }
    }
}

extern "C" void kernel_launch(void* const* d_in, const int* in_sizes, int n_in,
                              void* d_out, int out_size, void* d_ws, size_t ws_size,
                              hipStream_t stream) {
    const float* x_hat  = (const float*)d_in[0];
    const float* points = (const float*)d_in[1];
    const float* lik    = (const float*)d_in[2];
    float* out = (float*)d_out;
    float* wssum  = (float*)d_ws;          // 4 floats: sums + ticket
    float* wspart = (float*)d_ws + 16;     // 16 planes x 65536 floats = 4 MB

    hipMemsetAsync(wssum, 0, 16, stream);
    chamfer_kernel<<<DIRS * NB * QSLICES, 256, 0, stream>>>(x_hat, points, wspart);
    reduce_kernel<<<256, 256, 0, stream>>>(wspart, lik, wssum, out);
}

// Round 9
// 45.965 us; speedup vs baseline: 2.1034x; 1.1219x over previous
//
#include <hip/hip_runtime.h>
#include <math.h>

#define NB 8
#define PP 4096
#define MM 2048
#define DIRS 2
#define QSLICES 32
#define QS (PP / QSLICES)       // 128 q's staged per block
#define NPTS 16                 // points per thread -> PCHUNK = 4096 = PP
#define NMIN (DIRS * NB * PP)   // 65536 slots
#define NLIK (NB * MM)          // 16384

// ---------------- chamfer partial mins ----------------
// grid = 2*8*32 = 512 blocks x 256 threads (2 blocks/CU, 2 waves/SIMD).
// Each thread owns 16 p's (all of PP per block), scans a 128-q LDS slice
// with 1-ahead register prefetch. LDS pipe per CU per pair: 8 waves x 2
// b128 x 12cyc = 192 cyc vs VALU 448 cyc/SIMD -> VALU-bound with overlap.
__global__ __launch_bounds__(256, 2) void chamfer_kernel(const float* __restrict__ x,
                                                         const float* __restrict__ y,
                                                         float* __restrict__ wspart) {
    int bx = blockIdx.x;
    int qs  = bx & (QSLICES - 1); bx >>= 5;
    int n   = bx & (NB - 1);      bx >>= 3;
    int dir = bx;
    const float* a = dir ? y : x;
    const float* b = dir ? x : y;
    const float* an = a + (size_t)n * PP * 3;
    const float* bn = b + (size_t)n * PP * 3;

    __shared__ float4 lds[QS + 2];   // +2 pad: prefetch overrun is harmless
    int t = threadIdx.x;

    float X0[NPTS], X1[NPTS], X2[NPTS], XS[NPTS], M[NPTS];
    #pragma unroll
    for (int i = 0; i < NPTS; ++i) {
        int p = i * 256 + t;
        const float* ap = an + (size_t)p * 3;
        X0[i] = ap[0]; X1[i] = ap[1]; X2[i] = ap[2];
        XS[i] = X0[i] * X0[i] + X1[i] * X1[i] + X2[i] * X2[i];
        M[i] = INFINITY;
    }

    if (t < QS) {   // stage q-slice: lds[q] = {-2y0, -2y1, -2y2, |y|^2}
        int q = qs * QS + t;
        const float* bp = bn + (size_t)q * 3;
        float y0 = bp[0], y1 = bp[1], y2 = bp[2];
        lds[t] = make_float4(-2.f * y0, -2.f * y1, -2.f * y2,
                             y0 * y0 + y1 * y1 + y2 * y2);
        if (t < 2) lds[QS + t] = make_float4(0.f, 0.f, 0.f, 0.f);
    }
    __syncthreads();

    // 1-ahead register prefetch: consume pair j while loading pair j+1
    float4 A = lds[0], B = lds[1];
    for (int j = 0; j < QS / 2; ++j) {
        float4 A2 = lds[2 * j + 2];
        float4 B2 = lds[2 * j + 3];
        #pragma unroll
        for (int i = 0; i < NPTS; ++i) {
            float d0 = fmaf(X0[i], A.x, fmaf(X1[i], A.y, fmaf(X2[i], A.z, A.w)));
            float d1 = fmaf(X0[i], B.x, fmaf(X1[i], B.y, fmaf(X2[i], B.z, B.w)));
            M[i] = fminf(fminf(M[i], d0), d1);   // v_min3_f32
        }
        A = A2; B = B2;
    }

    float* plane = wspart + (size_t)qs * NMIN;
    int slot = (dir * NB + n) * PP + t;
    #pragma unroll
    for (int i = 0; i < NPTS; ++i)
        plane[slot + i * 256] = M[i] + XS[i];   // coalesced, no atomics, no init
}

// ---------------- reduce planes + log2sum + finalize (fused) ----------------
__global__ __launch_bounds__(256) void reduce_kernel(const float* __restrict__ wspart,
                                                     const float* __restrict__ lik,
                                                     float* __restrict__ wssum,  // [0..2]=sums, [3]=ticket
                                                     float* __restrict__ out) {
    int t = blockIdx.x * 256 + threadIdx.x;
    float m = wspart[t];
    #pragma unroll
    for (int s = 1; s < QSLICES; ++s)
        m = fminf(m, wspart[(size_t)s * NMIN + t]);

    float l = 0.f;
    if (t < NLIK) l = __log2f(lik[t]);

    #pragma unroll
    for (int off = 32; off > 0; off >>= 1) {
        m += __shfl_down(m, off, 64);
        l += __shfl_down(l, off, 64);
    }
    __shared__ float rm[4], rl[4];
    int lane = threadIdx.x & 63, wid = threadIdx.x >> 6;
    if (lane == 0) { rm[wid] = m; rl[wid] = l; }
    __syncthreads();
    if (threadIdx.x == 0) {
        int dir = blockIdx.x >> 7;
        atomicAdd(&wssum[dir], rm[0] + rm[1] + rm[2] + rm[3]);
        if (blockIdx.x < 64)
            atomicAdd(&wssum[2], rl[0] + rl[1] + rl[2] + rl[3]);
        __threadfence();
        unsigned done = atomicAdd((unsigned*)&wssum[3], 1u);
        if (done == 255u) {
            __threadfence();
            float s0 = __hip_atomic_load(&wssum[0], __ATOMIC_ACQUIRE, __HIP_MEMORY_SCOPE_AGENT);
            float s1 = __hip_atomic_load(&wssum[1], __ATOMIC_ACQUIRE, __HIP_MEMORY_SCOPE_AGENT);
            float s2 = __hip_atomic_load(&wssum[2], __ATOMIC_ACQUIRE, __HIP_MEMORY_SCOPE_AGENT);
            float rec = s0 / (float)(NB * PP) + s1 / (float)(NB * PP);
            float bit_y = s2 / (-(float)NB);
            float bpp = bit_y / (float)PP;
            out[0] = bpp + 1.0f * rec;  // loss (LMBDA = 1)
            out[1] = bpp;               // bpp_loss
            out[2] = rec;               // rec_loss
            out[3] = bit_y;             // bit_loss
            out[4] = bpp;               // bpp_y
        }
    }
}

extern "C" void kernel_launch(void* const* d_in, const int* in_sizes, int n_in,
                              void* d_out, int out_size, void* d_ws, size_t ws_size,
                              hipStream_t stream) {
    const float* x_hat  = (const float*)d_in[0];
    const float* points = (const float*)d_in[1];
    const float* lik    = (const float*)d_in[2];
    float* out = (float*)d_out;
    float* wssum  = (float*)d_ws;          // 4 floats: sums + ticket
    float* wspart = (float*)d_ws + 16;     // 32 planes x 65536 floats = 8 MB

    hipMemsetAsync(wssum, 0, 16, stream);
    chamfer_kernel<<<DIRS * NB * QSLICES, 256, 0, stream>>>(x_hat, points, wspart);
    reduce_kernel<<<256, 256, 0, stream>>>(wspart, lik, wssum, out);
}